// Round 1
// baseline (526.608 us; speedup 1.0000x reference)
//
#include <hip/hip_runtime.h>
#include <math.h>

// Problem shape (fixed by reference setup_inputs)
#define BATCH 32
#define SEQ   4096
#define HID   768
#define HV4   (HID / 4)                      // 192 float4 per row
#define CHUNKS 64                            // chunks per batch
#define ROWS_PER_BLOCK (SEQ / CHUNKS)        // 64
#define NWAVES 4
#define TROWS 8                              // rows per LDS tile (24 KB)
#define NT    (ROWS_PER_BLOCK / TROWS)       // 8 tiles per block
#define TILE_F4 (TROWS * HV4)                // 1536 float4 per tile
#define WAVE_F4 (TILE_F4 / NWAVES)           // 384 float4 staged per wave
#define CALLS   (WAVE_F4 / 64)               // 6 global_load_lds per wave per tile

typedef __attribute__((ext_vector_type(4))) float f4v;

__device__ __forceinline__ float dot4(f4v a, f4v b) {
  return a.x * b.x + a.y * b.y + a.z * b.z + a.w * b.w;
}

// Async 16B/lane global->LDS DMA. Dest is wave-uniform base + lane*16 —
// our layout is linear so per-lane dst pointers match the HW pattern.
__device__ __forceinline__ void async_copy16(const f4v* g, f4v* l) {
  __builtin_amdgcn_global_load_lds(
      (const __attribute__((address_space(1))) void*)g,
      (__attribute__((address_space(3))) void*)l,
      16, 0, 0);
}

// Pass 1: one block per (chunk, batch). hidden is streamed ONCE via async
// global_load_lds double-buffered tiles (in-flight bytes decoupled from VGPRs
// -> HBM-saturated instead of latency-bound). Online softmax per wave over
// 2 rows per tile x 8 tiles = 16 rows; block combines 4 wave partials in LDS.
__global__ __launch_bounds__(256, 3)
void attn_pass1(const float* __restrict__ hidden,
                const float* __restrict__ q,
                float* __restrict__ m_ws,
                float* __restrict__ l_ws,
                float* __restrict__ o_ws) {
  __shared__ float lds[2][TROWS * HID];      // 2 x 24 KB double buffer
  __shared__ float s_m[NWAVES], s_l[NWAVES];

  const int chunk = blockIdx.x;
  const int b     = blockIdx.y;
  const int tid   = threadIdx.x;
  const int wave  = tid >> 6;
  const int lane  = tid & 63;

  // Query fragment for this lane: floats 4*lane.. , +256, +512
  const f4v* q4 = reinterpret_cast<const f4v*>(q);
  const f4v qa = q4[lane];
  const f4v qb = q4[lane + 64];
  const f4v qc = q4[lane + 128];

  const f4v* gbase = reinterpret_cast<const f4v*>(hidden)
                   + ((size_t)b * SEQ + (size_t)chunk * ROWS_PER_BLOCK) * HV4;
  f4v* l0 = reinterpret_cast<f4v*>(lds[0]);
  f4v* l1 = reinterpret_cast<f4v*>(lds[1]);
  const int si = wave * WAVE_F4 + lane;      // this lane's f4 slot within a tile

  // Prologue: stage tiles 0 and 1 (12 async calls outstanding per wave)
  #pragma unroll
  for (int c = 0; c < CALLS; ++c)
    async_copy16(gbase + 0 * TILE_F4 + si + c * 64, l0 + si + c * 64);
  #pragma unroll
  for (int c = 0; c < CALLS; ++c)
    async_copy16(gbase + 1 * TILE_F4 + si + c * 64, l1 + si + c * 64);

  float m = -INFINITY;
  float l = 0.0f;
  f4v oa = (f4v)0.0f;
  f4v ob = (f4v)0.0f;
  f4v oc = (f4v)0.0f;

  #pragma unroll
  for (int t = 0; t < NT; ++t) {
    f4v* lb = (t & 1) ? l1 : l0;

    // Wait for THIS tile's DMA (keep next tile's 6 loads in flight), then
    // raw barrier. __syncthreads() would drain vmcnt(0) and kill the pipe.
    __builtin_amdgcn_sched_barrier(0);
    if (t < NT - 1) asm volatile("s_waitcnt vmcnt(6)" ::: "memory");
    else            asm volatile("s_waitcnt vmcnt(0)" ::: "memory");
    __builtin_amdgcn_s_barrier();
    __builtin_amdgcn_sched_barrier(0);

    // Wave computes rows (2*wave, 2*wave+1) of this tile.
    const f4v* r0 = lb + (size_t)(2 * wave + 0) * HV4;
    const f4v* r1 = lb + (size_t)(2 * wave + 1) * HV4;
    const f4v a0 = r0[lane], b0 = r0[lane + 64], c0 = r0[lane + 128];
    const f4v a1 = r1[lane], b1 = r1[lane + 64], c1 = r1[lane + 128];

    float p0 = dot4(a0, qa) + dot4(b0, qb) + dot4(c0, qc);
    float p1 = dot4(a1, qa) + dot4(b1, qb) + dot4(c1, qc);
    #pragma unroll
    for (int off = 32; off >= 1; off >>= 1) {
      p0 += __shfl_xor(p0, off, 64);
      p1 += __shfl_xor(p1, off, 64);
    }

    const float gm = fmaxf(p0, p1);
    if (gm > m) {                       // wave-uniform branch
      const float a = __expf(m - gm);   // exp(-inf)=0 on first tile
      l *= a;
      oa *= a; ob *= a; oc *= a;
      m = gm;
    }
    const float e0 = __expf(p0 - m);
    const float e1 = __expf(p1 - m);
    l += e0 + e1;
    oa += e0 * a0 + e1 * a1;
    ob += e0 * b0 + e1 * b1;
    oc += e0 * c0 + e1 * c1;

    // All ds_reads retired before the WAR barrier, then refill this buffer.
    asm volatile("s_waitcnt lgkmcnt(0)" ::: "memory");
    __builtin_amdgcn_sched_barrier(0);
    __builtin_amdgcn_s_barrier();
    __builtin_amdgcn_sched_barrier(0);

    if (t + 2 < NT) {
      #pragma unroll
      for (int c = 0; c < CALLS; ++c)
        async_copy16(gbase + (size_t)(t + 2) * TILE_F4 + si + c * 64,
                     lb + si + c * 64);
    }
  }

  // Combine the 4 wave partials. Reuse lds[0] (12 KB needed, 24 KB there);
  // safe: final loop barrier ensured all waves finished reading both buffers.
  float (*s_o)[HID] = reinterpret_cast<float(*)[HID]>(lds[0]);
  f4v* so4 = reinterpret_cast<f4v*>(s_o[wave]);
  so4[lane]       = oa;
  so4[lane + 64]  = ob;
  so4[lane + 128] = oc;
  if (lane == 0) { s_m[wave] = m; s_l[wave] = l; }
  __syncthreads();

  const float mb = fmaxf(fmaxf(s_m[0], s_m[1]), fmaxf(s_m[2], s_m[3]));
  const float w0 = __expf(s_m[0] - mb);
  const float w1 = __expf(s_m[1] - mb);
  const float w2 = __expf(s_m[2] - mb);
  const float w3 = __expf(s_m[3] - mb);
  const float lsum = w0 * s_l[0] + w1 * s_l[1] + w2 * s_l[2] + w3 * s_l[3];

  const int pidx = b * CHUNKS + chunk;
  float* O = o_ws + (size_t)pidx * HID;
  #pragma unroll
  for (int j = 0; j < 3; ++j) {
    const int h = tid + 256 * j;
    O[h] = w0 * s_o[0][h] + w1 * s_o[1][h] + w2 * s_o[2][h] + w3 * s_o[3][h];
  }
  if (tid == 0) { m_ws[pidx] = mb; l_ws[pidx] = lsum; }
}

// Pass 2: one thread per output element. grid (BATCH, 6) x 128 threads.
// m/l loads are redundant per thread but fully L2-resident (8 KB total).
__global__ __launch_bounds__(128)
void attn_pass2(const float* __restrict__ m_ws,
                const float* __restrict__ l_ws,
                const float* __restrict__ o_ws,
                float* __restrict__ out) {
  const int b = blockIdx.x;
  const int h = blockIdx.y * 128 + threadIdx.x;

  float mg = -INFINITY;
  #pragma unroll 8
  for (int c = 0; c < CHUNKS; ++c)
    mg = fmaxf(mg, m_ws[b * CHUNKS + c]);

  float L = 0.0f;
  float acc = 0.0f;
  #pragma unroll 8
  for (int c = 0; c < CHUNKS; ++c) {
    const int pi = b * CHUNKS + c;
    const float a = __expf(m_ws[pi] - mg);
    L += a * l_ws[pi];
    acc += a * o_ws[(size_t)pi * HID + h];
  }
  out[(size_t)b * HID + h] = acc / L;
}

extern "C" void kernel_launch(void* const* d_in, const int* in_sizes, int n_in,
                              void* d_out, int out_size, void* d_ws, size_t ws_size,
                              hipStream_t stream) {
  const float* hidden = (const float*)d_in[0];   // [32, 4096, 768] fp32
  const float* q      = (const float*)d_in[1];   // [1, 768] fp32
  float* out = (float*)d_out;                    // [32, 768] fp32

  // Workspace layout: m[2048] | l[2048] | O[2048*768]  (~6.3 MB total)
  float* m_ws = (float*)d_ws;
  float* l_ws = m_ws + BATCH * CHUNKS;
  float* o_ws = l_ws + BATCH * CHUNKS;

  dim3 grid1(CHUNKS, BATCH);
  attn_pass1<<<grid1, 256, 0, stream>>>(hidden, q, m_ws, l_ws, o_ws);
  dim3 grid2(BATCH, HID / 128);
  attn_pass2<<<grid2, 128, 0, stream>>>(m_ws, l_ws, o_ws, out);
}